// Round 2
// 114.213 us; speedup vs baseline: 1.0206x; 1.0206x over previous
//
#include <hip/hip_runtime.h>
#include <math.h>

// y[b,f,t] = | x[t] - C_f*w_f * S[t] |,  S[t] = sum_{j=0}^{497} a^j x[t-1-j] (edge-padded)
//
// R5 = R4 resubmitted (R4 bench died on container acquire, not on the kernel).
// One block per row (16 waves x 64 lanes = 1024 thr). Each wave's main float4
// loads double as the LDS staging stores for the whole 32KB row; after one
// barrier the warm-up window AND the lag window come from LDS. x becomes a
// read-ONCE stream from HBM (R3 paid a cross-XCD re-fetch of the preceding
// chunk on every 4th chunk). Math identical to R3 (which passed, absmax 3.9e-3).

constexpr int T     = 8000;
constexpr int F     = 64;
constexpr int B     = 32;
constexpr int KM1   = 498;
constexpr int CHUNK = 512;                       // samples per wave (8/lane)
constexpr int CPR   = 16;                        // chunks (waves) per row

#define DPP_F(x, ctrl, rm) \
  __builtin_bit_cast(float, __builtin_amdgcn_update_dpp(0, __builtin_bit_cast(int, (x)), (ctrl), (rm), 0xf, false))

__device__ __forceinline__ double dpow(double b, int e) {
    double r = 1.0, p = b;
    while (e) { if (e & 1) r *= p; p *= p; e >>= 1; }
    return r;
}

// branch-free float base^e, e in [0, 512)
__device__ __forceinline__ float powi(float base, int e) {
    float r = 1.0f, p = base;
    #pragma unroll
    for (int b = 0; b < 9; ++b) { r = (e & (1 << b)) ? r * p : r; p *= p; }
    return r;
}

__global__ __launch_bounds__(1024, 1) void willmore_scan_kernel(
    const float* __restrict__ x, const float* __restrict__ a,
    const float* __restrict__ w, float* __restrict__ out)
{
    __shared__ float lx[CPR * CHUNK];    // 32 KB: the whole row, staged once

    const int chunk = threadIdx.x >> 6;  // 0..15, one wave per chunk
    const int lane  = threadIdx.x & 63;
    const int row   = blockIdx.x;        // b*F + f
    const int f     = row & (F - 1);

    const float* xr   = x   + (size_t)row * T;
    float*       orow = out + (size_t)row * T;

    const int t0   = chunk * CHUNK;
    const int tb_u = t0 + 8 * lane;          // unclamped output base
    const int tb   = min(tb_u, T - 8);       // clamp bites only in chunk 15

    // ---- issue the (only) global loads up front ----
    const float4 m0 = *(const float4*)(xr + tb);
    const float4 m1 = *(const float4*)(xr + tb + 4);

    // ---- per-row constants, computed while loads are in flight ----
    const double ad     = (double)a[f];
    const double a498d  = dpow(ad, KM1);
    const double sumgeo = (1.0 - a498d) / (1.0 - ad);
    const double r_d    = dpow(ad, 8);
    const float  af     = (float)ad;
    const float  na498  = (float)(-a498d);
    const float  g      = (float)(1.0 / sumgeo) * w[f];
    const float  r1     = (float)r_d;
    const float  r2     = (float)(r_d * r_d);
    const float  r4     = (float)dpow(r_d, 4);
    const float  r8     = (float)dpow(r_d, 8);
    const float  inv_r  = (float)(1.0 / r_d);
    const float  alane  = powi(af, 8 * lane);                  // a^(8*lane)
    const float  wA     = powi(af, 8 * ((lane & 15) + 1));     // bcast15 weight
    const float  wB     = powi(af, 8 * ((lane & 31) + 1));     // bcast31 weight

    // ---- stage to LDS (chunk-15 clamped lanes write duplicates: benign) ----
    *(float4*)(&lx[tb])     = m0;
    *(float4*)(&lx[tb + 4]) = m1;
    __syncthreads();

    // ---- warm-up: S = S[t0] = sum_{j=0}^{497} a^j x[t0-1-j], from LDS ----
    float S;
    if (chunk == 0) {
        S = lx[0] * (float)sumgeo;           // broadcast read, edge-pad closed form
    } else {
        const int wb = t0 - CHUNK + 8 * lane;        // [t0-512, t0)
        const float4 w0 = *(const float4*)(&lx[wb]);
        const float4 w1 = *(const float4*)(&lx[wb + 4]);
        float ws8[8] = {w0.x, w0.y, w0.z, w0.w, w1.x, w1.y, w1.z, w1.w};
        // idx = t0-512+8*lane+i has j = 511-8*lane-i; drop j>497 (8*lane+i<14)
        #pragma unroll
        for (int i = 0; i < 8; ++i) { if (8 * lane + i < 14) ws8[i] = 0.0f; }
        float h = ws8[0];
        #pragma unroll
        for (int i = 1; i < 8; ++i) h = fmaf(h, af, ws8[i]);
        float contrib = powi(af, 504 - 8 * lane) * h;
        #pragma unroll
        for (int s = 1; s < 64; s <<= 1) contrib += __shfl_xor(contrib, s, 64);
        S = contrib;
    }

    // ---- lag window x[tb-498 .. tb-491] from LDS (edge-pad clamps to x[0]) ----
    const int lg = tb - KM1;
    float lv[8];
    #pragma unroll
    for (int i = 0; i < 8; ++i) lv[i] = lx[max(lg + i, 0)];

    // ---- main: u, lane aggregate, DPP weighted scan (ratio a^8) ----
    const float xv[8] = {m0.x, m0.y, m0.z, m0.w, m1.x, m1.y, m1.z, m1.w};
    float u[8];
    #pragma unroll
    for (int i = 0; i < 8; ++i) u[i] = fmaf(na498, lv[i], xv[i]);

    float q = u[0];
    #pragma unroll
    for (int i = 1; i < 8; ++i) q = fmaf(q, af, u[i]);

    float G = q;
    G = fmaf(r1, DPP_F(G, 0x111, 0xf), G);   // row_shr:1
    G = fmaf(r2, DPP_F(G, 0x112, 0xf), G);   // row_shr:2
    G = fmaf(r4, DPP_F(G, 0x114, 0xf), G);   // row_shr:4
    G = fmaf(r8, DPP_F(G, 0x118, 0xf), G);   // row_shr:8
    G = fmaf(wA, DPP_F(G, 0x142, 0xa), G);   // row_bcast15 -> rows 1,3
    G = fmaf(wB, DPP_F(G, 0x143, 0xc), G);   // row_bcast31 -> rows 2,3

    const float E = (G - q) * inv_r;         // exclusive prefix (exact 0 at lane 0)

    float s = fmaf(alane, S, E);             // S[t0 + 8*lane]
    float y[8];
    #pragma unroll
    for (int i = 0; i < 8; ++i) {
        y[i] = fabsf(fmaf(-g, s, xv[i]));
        s = fmaf(af, s, u[i]);
    }

    if (tb_u <= T - 8) {
        *(float4*)(orow + tb)     = make_float4(y[0], y[1], y[2], y[3]);
        *(float4*)(orow + tb + 4) = make_float4(y[4], y[5], y[6], y[7]);
    }
}

extern "C" void kernel_launch(void* const* d_in, const int* in_sizes, int n_in,
                              void* d_out, int out_size, void* d_ws, size_t ws_size,
                              hipStream_t stream) {
    const float* x = (const float*)d_in[0];
    const float* a = (const float*)d_in[1];
    const float* w = (const float*)d_in[2];
    float* out = (float*)d_out;

    // one block per (b,f) row: 2048 blocks x 16 waves
    hipLaunchKernelGGL(willmore_scan_kernel, dim3(B * F), dim3(1024), 0, stream,
                       x, a, w, out);
}